// Round 1
// baseline (305.486 us; speedup 1.0000x reference)
//
#include <hip/hip_runtime.h>
#include <hip/hip_bf16.h>
#include <cstdint>

// Problem constants
#define NTOK 8192
#define DIN  1024
#define DOUT 1024
#define NEXP 8

typedef __attribute__((ext_vector_type(8))) __bf16 bf16x8;
typedef __attribute__((ext_vector_type(4))) float f32x4;

__device__ __forceinline__ unsigned short f2bf(float f) {
    unsigned int u = __builtin_bit_cast(unsigned int, f);
    u += 0x7FFFu + ((u >> 16) & 1u);   // round-to-nearest-even
    return (unsigned short)(u >> 16);
}

__device__ __forceinline__ void cp16(const void* gsrc, void* ldst) {
    __builtin_amdgcn_global_load_lds(
        (const __attribute__((address_space(1))) void*)gsrc,
        (__attribute__((address_space(3))) void*)ldst,
        16, 0, 0);
}

// ---------------------------------------------------------------------------
// Kernel 1: fused gate (softmax(x@Wg+bg)) + x -> bf16 conversion.
// One wave per token; 2048 blocks x 256 threads (4 waves).
// ---------------------------------------------------------------------------
__global__ __launch_bounds__(256) void gate_convx_kernel(
    const float* __restrict__ x, const float* __restrict__ Wg,
    const float* __restrict__ bg, unsigned short* __restrict__ xb,
    float* __restrict__ g)
{
    int lane = threadIdx.x & 63;
    int wave = threadIdx.x >> 6;
    int n = blockIdx.x * 4 + wave;

    const float* xr = x + (size_t)n * DIN;
    unsigned short* xbr = xb + (size_t)n * DIN;

    float a0=0,a1=0,a2=0,a3=0,a4=0,a5=0,a6=0,a7=0;

#pragma unroll
    for (int c = 0; c < 4; ++c) {
        int k = c * 256 + lane * 4;
        float4 v = *(const float4*)&xr[k];
        ushort4 u;
        u.x = f2bf(v.x); u.y = f2bf(v.y); u.z = f2bf(v.z); u.w = f2bf(v.w);
        *(ushort4*)&xbr[k] = u;
#pragma unroll
        for (int i = 0; i < 4; ++i) {
            float xv = (i == 0) ? v.x : (i == 1) ? v.y : (i == 2) ? v.z : v.w;
            float4 w0 = *(const float4*)&Wg[(size_t)(k + i) * NEXP];
            float4 w1 = *(const float4*)&Wg[(size_t)(k + i) * NEXP + 4];
            a0 += xv * w0.x; a1 += xv * w0.y; a2 += xv * w0.z; a3 += xv * w0.w;
            a4 += xv * w1.x; a5 += xv * w1.y; a6 += xv * w1.z; a7 += xv * w1.w;
        }
    }

#pragma unroll
    for (int off = 32; off > 0; off >>= 1) {
        a0 += __shfl_xor(a0, off, 64);
        a1 += __shfl_xor(a1, off, 64);
        a2 += __shfl_xor(a2, off, 64);
        a3 += __shfl_xor(a3, off, 64);
        a4 += __shfl_xor(a4, off, 64);
        a5 += __shfl_xor(a5, off, 64);
        a6 += __shfl_xor(a6, off, 64);
        a7 += __shfl_xor(a7, off, 64);
    }

    float l[8] = {a0,a1,a2,a3,a4,a5,a6,a7};
    float m = -1e30f;
#pragma unroll
    for (int e = 0; e < 8; ++e) { l[e] += bg[e]; m = fmaxf(m, l[e]); }
    float s = 0.f;
#pragma unroll
    for (int e = 0; e < 8; ++e) { l[e] = __expf(l[e] - m); s += l[e]; }
    float inv = 1.0f / s;

    if (lane == 0) {
        float4 p0 = make_float4(l[0]*inv, l[1]*inv, l[2]*inv, l[3]*inv);
        float4 p1 = make_float4(l[4]*inv, l[5]*inv, l[6]*inv, l[7]*inv);
        *(float4*)&g[(size_t)n * 8]     = p0;
        *(float4*)&g[(size_t)n * 8 + 4] = p1;
    }
}

// ---------------------------------------------------------------------------
// Kernel 2: We [e][k][o] fp32  ->  WebT [e][o][k] bf16 (transpose + convert).
// 64x64 tiles via LDS. 8*16*16 = 2048 blocks x 256 threads.
// ---------------------------------------------------------------------------
__global__ __launch_bounds__(256) void conv_we_kernel(
    const float* __restrict__ We, unsigned short* __restrict__ wt)
{
    __shared__ unsigned short tile[64 * 72];

    int b = blockIdx.x;
    int e  = b >> 8;
    int kt = (b >> 4) & 15;
    int ot = b & 15;

    const float* src = We + ((size_t)e << 20) + (size_t)(kt * 64) * DOUT + ot * 64;
    unsigned short* dst = wt + ((size_t)e << 20) + (size_t)(ot * 64) * DIN + kt * 64;

    int t = threadIdx.x;
    int kl = t >> 2;
    int og = (t & 3) * 16;
#pragma unroll
    for (int c = 0; c < 4; ++c) {
        int o = og + c * 4;
        float4 v = *(const float4*)&src[(size_t)kl * DOUT + o];
        ushort4 u;
        u.x = f2bf(v.x); u.y = f2bf(v.y); u.z = f2bf(v.z); u.w = f2bf(v.w);
        *(ushort4*)&tile[kl * 72 + o] = u;
    }
    __syncthreads();
    int ol = t >> 2;
    int kg = (t & 3) * 16;
    unsigned short tmp[16];
#pragma unroll
    for (int i = 0; i < 16; ++i) tmp[i] = tile[(kg + i) * 72 + ol];
    *(uint4*)&dst[(size_t)ol * DIN + kg]     = *(uint4*)&tmp[0];
    *(uint4*)&dst[(size_t)ol * DIN + kg + 8] = *(uint4*)&tmp[8];
}

// ---------------------------------------------------------------------------
// Kernel 3: main MoE GEMM.
// out[n,o] = sum_e g[n,e] * ( (xb @ WebT[e]^T)[n,o] + be[e,o] )
// 128x128 tile, BK=64, 4 waves, 16x16x32 bf16 MFMA, global_load_lds staging.
// Grid = 64 * 8 = 512 blocks; bid%8 = bn -> XCD-local WebT slab.
// ---------------------------------------------------------------------------
__global__ __launch_bounds__(256, 2) void moe_gemm_kernel(
    const unsigned short* __restrict__ xb,   // [NTOK][DIN] bf16
    const unsigned short* __restrict__ wt,   // [E][DOUT][DIN] bf16
    const float* __restrict__ g,             // [NTOK][E]
    const float* __restrict__ be,            // [E][DOUT]
    float* __restrict__ out)                 // [NTOK][DOUT]
{
    __shared__ unsigned short lA[128 * 64];
    __shared__ unsigned short lB[128 * 64];
    __shared__ float lG[128 * 8];
    __shared__ float lBias[8 * 128];

    int bid = blockIdx.x;
    int bn = bid & 7;
    int bm = bid >> 3;
    int tid = threadIdx.x;
    int lane = tid & 63;
    int wave = tid >> 6;
    int wm = wave >> 1;        // 0..1
    int wn = wave & 1;         // 0..1

    // stage gate block [128 rows][8 experts] and bias block [8][128 cols]
    {
        int r = tid >> 1, c = (tid & 1) * 4;
        *(float4*)&lG[tid * 4] = *(const float4*)&g[(size_t)(bm * 128 + r) * 8 + c];
#pragma unroll
        for (int q = 0; q < 4; ++q) {
            int idx = q * 256 + tid;                 // 0..1023
            lBias[idx] = be[(size_t)(idx >> 7) * DOUT + bn * 128 + (idx & 127)];
        }
    }

    f32x4 outAcc[4][4] = {};

    const unsigned short* aBase = xb + (size_t)(bm * 128) * DIN;
    const unsigned short* bBase0 = wt + (size_t)(bn * 128) * DIN;

    int rowS = wave * 8 + (lane >> 3);   // staging row within 32-row group
    int k8   = (lane & 7) * 8;           // staging k offset
    int rA   = lane & 15;                // fragment row/col
    int kq   = (lane >> 4) * 8;          // fragment k chunk

    for (int e = 0; e < NEXP; ++e) {
        f32x4 acc[4][4] = {};
        const unsigned short* bBase = bBase0 + ((size_t)e << 20);

        for (int kt = 0; kt < 16; ++kt) {
            int kb = kt * 64;
            __syncthreads();
#pragma unroll
            for (int j = 0; j < 4; ++j) {
                int row = j * 32 + rowS;
                cp16(aBase + (size_t)row * DIN + kb + k8,
                     &lA[j * 2048 + wave * 512]);
                cp16(bBase + (size_t)row * DIN + kb + k8,
                     &lB[j * 2048 + wave * 512]);
            }
            __syncthreads();
#pragma unroll
            for (int ks = 0; ks < 2; ++ks) {
                bf16x8 af[4], bfr[4];
#pragma unroll
                for (int i = 0; i < 4; ++i)
                    af[i] = *(const bf16x8*)&lA[(wm * 64 + i * 16 + rA) * 64 + ks * 32 + kq];
#pragma unroll
                for (int j = 0; j < 4; ++j)
                    bfr[j] = *(const bf16x8*)&lB[(wn * 64 + j * 16 + rA) * 64 + ks * 32 + kq];
#pragma unroll
                for (int i = 0; i < 4; ++i)
#pragma unroll
                    for (int j = 0; j < 4; ++j)
                        acc[i][j] = __builtin_amdgcn_mfma_f32_16x16x32_bf16(
                            af[i], bfr[j], acc[i][j], 0, 0, 0);
            }
        }

        // merge this expert: outAcc += g[row,e] * (acc + be[e,col])
        float bv[4];
#pragma unroll
        for (int j = 0; j < 4; ++j)
            bv[j] = lBias[e * 128 + wn * 64 + j * 16 + rA];
#pragma unroll
        for (int i = 0; i < 4; ++i) {
            int rb = wm * 64 + i * 16 + (lane >> 4) * 4;
            float g0 = lG[(rb + 0) * 8 + e];
            float g1 = lG[(rb + 1) * 8 + e];
            float g2 = lG[(rb + 2) * 8 + e];
            float g3 = lG[(rb + 3) * 8 + e];
#pragma unroll
            for (int j = 0; j < 4; ++j) {
                outAcc[i][j].x += g0 * (acc[i][j].x + bv[j]);
                outAcc[i][j].y += g1 * (acc[i][j].y + bv[j]);
                outAcc[i][j].z += g2 * (acc[i][j].z + bv[j]);
                outAcc[i][j].w += g3 * (acc[i][j].w + bv[j]);
            }
        }
    }

    // epilogue: C layout col = lane&15, row = (lane>>4)*4 + reg
#pragma unroll
    for (int i = 0; i < 4; ++i) {
        int rowb = bm * 128 + wm * 64 + i * 16 + (lane >> 4) * 4;
#pragma unroll
        for (int j = 0; j < 4; ++j) {
            int col = bn * 128 + wn * 64 + j * 16 + rA;
            out[(size_t)(rowb + 0) * DOUT + col] = outAcc[i][j].x;
            out[(size_t)(rowb + 1) * DOUT + col] = outAcc[i][j].y;
            out[(size_t)(rowb + 2) * DOUT + col] = outAcc[i][j].z;
            out[(size_t)(rowb + 3) * DOUT + col] = outAcc[i][j].w;
        }
    }
}

// ---------------------------------------------------------------------------
extern "C" void kernel_launch(void* const* d_in, const int* in_sizes, int n_in,
                              void* d_out, int out_size, void* d_ws, size_t ws_size,
                              hipStream_t stream)
{
    const float* x  = (const float*)d_in[0];   // [8192,1024]
    const float* We = (const float*)d_in[1];   // [8,1024,1024]
    const float* be = (const float*)d_in[2];   // [8,1024]
    const float* Wg = (const float*)d_in[3];   // [1024,8]
    const float* bg = (const float*)d_in[4];   // [8]
    float* out = (float*)d_out;                // [8192,1024]

    // workspace layout: xb (16.78MB bf16) | WebT (16.78MB bf16) | g (256KB f32)
    unsigned short* xb = (unsigned short*)d_ws;
    unsigned short* wt = xb + (size_t)NTOK * DIN;
    float* g = (float*)(wt + (size_t)NEXP * DOUT * DIN);

    gate_convx_kernel<<<NTOK / 4, 256, 0, stream>>>(x, Wg, bg, xb, g);
    conv_we_kernel<<<NEXP * 16 * 16, 256, 0, stream>>>(We, wt);
    moe_gemm_kernel<<<(NTOK / 128) * (DOUT / 128), 256, 0, stream>>>(xb, wt, g, be, out);
}

// Round 2
// 264.212 us; speedup vs baseline: 1.1562x; 1.1562x over previous
//
#include <hip/hip_runtime.h>
#include <hip/hip_bf16.h>
#include <cstdint>

// Problem constants
#define NTOK 8192
#define DIN  1024
#define DOUT 1024
#define NEXP 8

typedef __attribute__((ext_vector_type(8))) __bf16 bf16x8;
typedef __attribute__((ext_vector_type(4))) float f32x4;

__device__ __forceinline__ unsigned short f2bf(float f) {
    unsigned int u = __builtin_bit_cast(unsigned int, f);
    u += 0x7FFFu + ((u >> 16) & 1u);   // round-to-nearest-even
    return (unsigned short)(u >> 16);
}

__device__ __forceinline__ void cp16(const void* gsrc, void* ldst) {
    __builtin_amdgcn_global_load_lds(
        (const __attribute__((address_space(1))) void*)gsrc,
        (__attribute__((address_space(3))) void*)ldst,
        16, 0, 0);
}

// ---------------------------------------------------------------------------
// Kernel 1: fused gate (softmax(x@Wg+bg)) + x -> bf16 conversion.
// One wave per token; 2048 blocks x 256 threads (4 waves).
// ---------------------------------------------------------------------------
__global__ __launch_bounds__(256) void gate_convx_kernel(
    const float* __restrict__ x, const float* __restrict__ Wg,
    const float* __restrict__ bg, unsigned short* __restrict__ xb,
    float* __restrict__ g)
{
    int lane = threadIdx.x & 63;
    int wave = threadIdx.x >> 6;
    int n = blockIdx.x * 4 + wave;

    const float* xr = x + (size_t)n * DIN;
    unsigned short* xbr = xb + (size_t)n * DIN;

    float a0=0,a1=0,a2=0,a3=0,a4=0,a5=0,a6=0,a7=0;

#pragma unroll
    for (int c = 0; c < 4; ++c) {
        int k = c * 256 + lane * 4;
        float4 v = *(const float4*)&xr[k];
        ushort4 u;
        u.x = f2bf(v.x); u.y = f2bf(v.y); u.z = f2bf(v.z); u.w = f2bf(v.w);
        *(ushort4*)&xbr[k] = u;
#pragma unroll
        for (int i = 0; i < 4; ++i) {
            float xv = (i == 0) ? v.x : (i == 1) ? v.y : (i == 2) ? v.z : v.w;
            float4 w0 = *(const float4*)&Wg[(size_t)(k + i) * NEXP];
            float4 w1 = *(const float4*)&Wg[(size_t)(k + i) * NEXP + 4];
            a0 += xv * w0.x; a1 += xv * w0.y; a2 += xv * w0.z; a3 += xv * w0.w;
            a4 += xv * w1.x; a5 += xv * w1.y; a6 += xv * w1.z; a7 += xv * w1.w;
        }
    }

#pragma unroll
    for (int off = 32; off > 0; off >>= 1) {
        a0 += __shfl_xor(a0, off, 64);
        a1 += __shfl_xor(a1, off, 64);
        a2 += __shfl_xor(a2, off, 64);
        a3 += __shfl_xor(a3, off, 64);
        a4 += __shfl_xor(a4, off, 64);
        a5 += __shfl_xor(a5, off, 64);
        a6 += __shfl_xor(a6, off, 64);
        a7 += __shfl_xor(a7, off, 64);
    }

    float l[8] = {a0,a1,a2,a3,a4,a5,a6,a7};
    float m = -1e30f;
#pragma unroll
    for (int e = 0; e < 8; ++e) { l[e] += bg[e]; m = fmaxf(m, l[e]); }
    float s = 0.f;
#pragma unroll
    for (int e = 0; e < 8; ++e) { l[e] = __expf(l[e] - m); s += l[e]; }
    float inv = 1.0f / s;

    if (lane == 0) {
        float4 p0 = make_float4(l[0]*inv, l[1]*inv, l[2]*inv, l[3]*inv);
        float4 p1 = make_float4(l[4]*inv, l[5]*inv, l[6]*inv, l[7]*inv);
        *(float4*)&g[(size_t)n * 8]     = p0;
        *(float4*)&g[(size_t)n * 8 + 4] = p1;
    }
}

// ---------------------------------------------------------------------------
// Kernel 2: We [e][k][o] fp32  ->  WebT [e][o][k] bf16 (transpose + convert).
// 64x64 tiles via LDS. 8*16*16 = 2048 blocks x 256 threads.
// ---------------------------------------------------------------------------
__global__ __launch_bounds__(256) void conv_we_kernel(
    const float* __restrict__ We, unsigned short* __restrict__ wt)
{
    __shared__ unsigned short tile[64 * 72];

    int b = blockIdx.x;
    int e  = b >> 8;
    int kt = (b >> 4) & 15;
    int ot = b & 15;

    const float* src = We + ((size_t)e << 20) + (size_t)(kt * 64) * DOUT + ot * 64;
    unsigned short* dst = wt + ((size_t)e << 20) + (size_t)(ot * 64) * DIN + kt * 64;

    int t = threadIdx.x;
    int kl = t >> 2;
    int og = (t & 3) * 16;
#pragma unroll
    for (int c = 0; c < 4; ++c) {
        int o = og + c * 4;
        float4 v = *(const float4*)&src[(size_t)kl * DOUT + o];
        ushort4 u;
        u.x = f2bf(v.x); u.y = f2bf(v.y); u.z = f2bf(v.z); u.w = f2bf(v.w);
        *(ushort4*)&tile[kl * 72 + o] = u;
    }
    __syncthreads();
    int ol = t >> 2;
    int kg = (t & 3) * 16;
    unsigned short tmp[16];
#pragma unroll
    for (int i = 0; i < 16; ++i) tmp[i] = tile[(kg + i) * 72 + ol];
    *(uint4*)&dst[(size_t)ol * DIN + kg]     = *(uint4*)&tmp[0];
    *(uint4*)&dst[(size_t)ol * DIN + kg + 8] = *(uint4*)&tmp[8];
}

// ---------------------------------------------------------------------------
// Kernel 3: main MoE GEMM.
// out[n,o] = sum_e g[n,e] * ( (xb @ WebT[e]^T)[n,o] + be[e,o] )
// 128x128 tile, BK=64, 4 waves, 16x16x32 bf16 MFMA, global_load_lds staging.
//
// LDS k-chunk XOR swizzle: logical element (row, k) lives at physical
//   row*64 + ((k/8) ^ (row&7))*8 + k%8.
// global_load_lds's LDS dest is fixed (base + lane*16B); the swizzle is
// realized by permuting each lane's *source* address (same 128B segments,
// coalescing unchanged). Kills the 16-way bank conflict of the unswizzled
// row-stride-128B fragment reads (R1: SQ_LDS_BANK_CONFLICT = 5.1e7).
//
// XCD-aware mapping: bid&7 selects an 8-row-tile A slab (2MB, fits one
// XCD's 4MB L2) so per-expert A re-stages hit L2 (R1: FETCH_SIZE 534MB
// from A-slab thrash with the bn-major mapping).
// ---------------------------------------------------------------------------
__global__ __launch_bounds__(256, 2) void moe_gemm_kernel(
    const unsigned short* __restrict__ xb,   // [NTOK][DIN] bf16
    const unsigned short* __restrict__ wt,   // [E][DOUT][DIN] bf16
    const float* __restrict__ g,             // [NTOK][E]
    const float* __restrict__ be,            // [E][DOUT]
    float* __restrict__ out)                 // [NTOK][DOUT]
{
    __shared__ unsigned short lA[128 * 64];
    __shared__ unsigned short lB[128 * 64];
    __shared__ float lG[128 * 8];
    __shared__ float lBias[8 * 128];

    int bid = blockIdx.x;
    // XCD-aware: assume round-robin bid->XCD; give each XCD a contiguous
    // 8-tile A slab (bm) and stream bn across it.
    int bm = (bid & 7) * 8 + ((bid >> 3) & 7);   // 0..63
    int bn = bid >> 6;                            // 0..7
    int tid = threadIdx.x;
    int lane = tid & 63;
    int wave = tid >> 6;
    int wm = wave >> 1;        // 0..1
    int wn = wave & 1;         // 0..1

    // stage gate block [128 rows][8 experts] and bias block [8][128 cols]
    {
        *(float4*)&lG[tid * 4] = *(const float4*)&g[(size_t)(bm * 128) * 8 + tid * 4];
#pragma unroll
        for (int q = 0; q < 4; ++q) {
            int idx = q * 256 + tid;                 // 0..1023
            lBias[idx] = be[(size_t)(idx >> 7) * DOUT + bn * 128 + (idx & 127)];
        }
    }

    f32x4 outAcc[4][4] = {};

    const unsigned short* aBase = xb + (size_t)(bm * 128) * DIN;
    const unsigned short* bBase0 = wt + (size_t)(bn * 128) * DIN;

    int rowS = wave * 8 + (lane >> 3);                    // staging row in 32-row group
    int k8   = (((lane & 7) ^ (lane >> 3)) * 8);          // swizzled source k offset
    int rA   = lane & 15;                                 // fragment row/col
    int swz  = rA & 7;                                    // row&7 for fragment rows

    for (int e = 0; e < NEXP; ++e) {
        f32x4 acc[4][4] = {};
        const unsigned short* bBase = bBase0 + ((size_t)e << 20);

        for (int kt = 0; kt < 16; ++kt) {
            int kb = kt * 64;
            __syncthreads();
#pragma unroll
            for (int j = 0; j < 4; ++j) {
                int row = j * 32 + rowS;
                cp16(aBase + (size_t)row * DIN + kb + k8,
                     &lA[j * 2048 + wave * 512]);
                cp16(bBase + (size_t)row * DIN + kb + k8,
                     &lB[j * 2048 + wave * 512]);
            }
            __syncthreads();
#pragma unroll
            for (int ks = 0; ks < 2; ++ks) {
                int kc = ks * 4 + (lane >> 4);            // logical k-chunk 0..7
                int kp = (kc ^ swz) * 8;                  // swizzled physical offset
                bf16x8 af[4], bfr[4];
#pragma unroll
                for (int i = 0; i < 4; ++i)
                    af[i] = *(const bf16x8*)&lA[(wm * 64 + i * 16 + rA) * 64 + kp];
#pragma unroll
                for (int j = 0; j < 4; ++j)
                    bfr[j] = *(const bf16x8*)&lB[(wn * 64 + j * 16 + rA) * 64 + kp];
#pragma unroll
                for (int i = 0; i < 4; ++i)
#pragma unroll
                    for (int j = 0; j < 4; ++j)
                        acc[i][j] = __builtin_amdgcn_mfma_f32_16x16x32_bf16(
                            af[i], bfr[j], acc[i][j], 0, 0, 0);
            }
        }

        // merge this expert: outAcc += g[row,e] * (acc + be[e,col])
        float bv[4];
#pragma unroll
        for (int j = 0; j < 4; ++j)
            bv[j] = lBias[e * 128 + wn * 64 + j * 16 + rA];
#pragma unroll
        for (int i = 0; i < 4; ++i) {
            int rb = wm * 64 + i * 16 + (lane >> 4) * 4;
            float g0 = lG[(rb + 0) * 8 + e];
            float g1 = lG[(rb + 1) * 8 + e];
            float g2 = lG[(rb + 2) * 8 + e];
            float g3 = lG[(rb + 3) * 8 + e];
#pragma unroll
            for (int j = 0; j < 4; ++j) {
                outAcc[i][j].x += g0 * (acc[i][j].x + bv[j]);
                outAcc[i][j].y += g1 * (acc[i][j].y + bv[j]);
                outAcc[i][j].z += g2 * (acc[i][j].z + bv[j]);
                outAcc[i][j].w += g3 * (acc[i][j].w + bv[j]);
            }
        }
    }

    // epilogue: C layout col = lane&15, row = (lane>>4)*4 + reg
#pragma unroll
    for (int i = 0; i < 4; ++i) {
        int rowb = bm * 128 + wm * 64 + i * 16 + (lane >> 4) * 4;
#pragma unroll
        for (int j = 0; j < 4; ++j) {
            int col = bn * 128 + wn * 64 + j * 16 + rA;
            out[(size_t)(rowb + 0) * DOUT + col] = outAcc[i][j].x;
            out[(size_t)(rowb + 1) * DOUT + col] = outAcc[i][j].y;
            out[(size_t)(rowb + 2) * DOUT + col] = outAcc[i][j].z;
            out[(size_t)(rowb + 3) * DOUT + col] = outAcc[i][j].w;
        }
    }
}

// ---------------------------------------------------------------------------
extern "C" void kernel_launch(void* const* d_in, const int* in_sizes, int n_in,
                              void* d_out, int out_size, void* d_ws, size_t ws_size,
                              hipStream_t stream)
{
    const float* x  = (const float*)d_in[0];   // [8192,1024]
    const float* We = (const float*)d_in[1];   // [8,1024,1024]
    const float* be = (const float*)d_in[2];   // [8,1024]
    const float* Wg = (const float*)d_in[3];   // [1024,8]
    const float* bg = (const float*)d_in[4];   // [8]
    float* out = (float*)d_out;                // [8192,1024]

    // workspace layout: xb (16.78MB bf16) | WebT (16.78MB bf16) | g (256KB f32)
    unsigned short* xb = (unsigned short*)d_ws;
    unsigned short* wt = xb + (size_t)NTOK * DIN;
    float* g = (float*)(wt + (size_t)NEXP * DOUT * DIN);

    gate_convx_kernel<<<NTOK / 4, 256, 0, stream>>>(x, Wg, bg, xb, g);
    conv_we_kernel<<<NEXP * 16 * 16, 256, 0, stream>>>(We, wt);
    moe_gemm_kernel<<<(NTOK / 128) * (DOUT / 128), 256, 0, stream>>>(xb, wt, g, be, out);
}